// Round 6
// baseline (356.114 us; speedup 1.0000x reference)
//
#include <hip/hip_runtime.h>
#include <hip/hip_bf16.h>
#include <stdint.h>

// Shapes (fixed): B=4, S=2048, D_MODEL=D_K=D_V=1024
#define SEQ   2048
#define DM    1024
#define NBAT  4

typedef __attribute__((ext_vector_type(8))) short  short8;   // 8 bf16 = 4 VGPRs (MFMA A/B frag)
typedef __attribute__((ext_vector_type(4))) float  floatx4;  // MFMA C/D frag

__device__ __forceinline__ unsigned short f2b(float f) {
    __hip_bfloat16 h = __float2bfloat16(f);
    unsigned short r;
    __builtin_memcpy(&r, &h, 2);
    return r;
}

__device__ __forceinline__ ushort4 pack4(float a, float b, float c, float d) {
    ushort4 u; u.x = f2b(a); u.y = f2b(b); u.z = f2b(c); u.w = f2b(d); return u;
}

// async global->LDS, 16B per lane. dst must be wave-uniform base (lane*16 added by HW).
__device__ __forceinline__ void gload16(const void* g, void* s) {
    __builtin_amdgcn_global_load_lds(
        (const __attribute__((address_space(1))) unsigned int*)(uintptr_t)g,
        (__attribute__((address_space(3))) unsigned int*)(uintptr_t)s,
        16, 0, 0);
}

// Fused prep: x cast (0..8191), Wq/Wk/Wv cast into wall (8192..11263),
// rowsum zero (11264..11295), zero d_out rows [1024,2048) per batch
// (11296..15391) for attn1's atomicAdd K-split blocks.
__global__ void prep(const float4* __restrict__ x,
                     const float4* __restrict__ w0, const float4* __restrict__ w1,
                     const float4* __restrict__ w2,
                     ushort4* __restrict__ xb, ushort4* __restrict__ wall,
                     float* __restrict__ rsum, float4* __restrict__ outz)
{
    const int b = blockIdx.x;
    const int t = threadIdx.x;
    if (b < 8192) {
        const int i = b * 256 + t;
        float4 f = x[i];
        xb[i] = pack4(f.x, f.y, f.z, f.w);
    } else if (b < 11264) {
        const int idx  = b - 8192;
        const int wsel = idx >> 10;
        const int i    = (idx & 1023) * 256 + t;
        const float4* src = (wsel == 0) ? w0 : (wsel == 1) ? w1 : w2;
        float4 f = src[i];
        wall[(size_t)wsel * 262144 + i] = pack4(f.x, f.y, f.z, f.w);
    } else if (b < 11296) {
        rsum[(b - 11264) * 256 + t] = 0.f;
    } else {                              // zero out rows [1024,2048) of each batch
        const int u = b - 11296;          // 0..4095
        const int z = u >> 10, idx = u & 1023;
        outz[(size_t)z * 524288 + 262144 + idx * 256 + t] = (float4){0.f, 0.f, 0.f, 0.f};
    }
}

// ---------------------------------------------------------------------------
// Unified 256x256 8-phase GEMM core (m196/m201-faithful: fine interleave +
// counted waits is the measured +28-41% lever; coarse splits measured NULL).
// BM=BN=256, BK=64, 8 waves (2M x 4N, wave tile 128x64 -> MFMA:ds_read=2.67).
// LDS = 2 buffers x 4 chunks x 16 KB = 128 KB. Chunk = [128 rows][64 k] bf16,
// R0/R3-proven zero-conflict layout (piece slot s of row R holds global piece
// s^(R&7); reads use slot (kk*4+q)^(r&7)).
// Per K-tile: 4 phases {ds_read 4-8 x b128 [+ stage 1 chunk-pair of t+1 in
// ph0/ph1] ; barrier ; lgkmcnt(0)+sched_barrier (rule 18) ; setprio(1) ;
// 16 MFMA ; setprio(0) ; barrier}; vmcnt(0) at ph3 (loads >=2 phases old).
// Hazards: WAR (stage t+1 vs reads t-1) separated by full barrier; RAW by
// ph3 vmcnt+barrier of tile t-1.
// EPI 0: QKV (unswapped operands; Q/K/Vt epilogue, qscale folded into Q).
// EPI 1: scores (swapped; E=exp causal bf16 ushort4 + rowsum atomics).
// EPI 2: PV (swapped; /rowsum; direct float4 store or atomicAdd for K-split).
// ---------------------------------------------------------------------------
template<int EPI>
__global__ __launch_bounds__(512, 2) void gemm8p(
    const unsigned short* __restrict__ Ag, const unsigned short* __restrict__ Bg,
    void* __restrict__ P0, void* __restrict__ P1, void* __restrict__ P2,
    float* __restrict__ rowsum, float qscale)
{
    __shared__ __align__(16) unsigned short lds[65536];   // 128 KB

    int m0, n0, start, cnt, ntl = 0, z = 0, atom = 0;
    const unsigned short* A;
    const unsigned short* Bm;
    size_t LDA, LDB;

    if (EPI == 0) {
        // 384 blocks = 8 XCDs x 48, bijective, mt-major per XCD.
        const int bid = blockIdx.x;
        const int wg  = (bid & 7) * 48 + (bid >> 3);
        const int mt  = wg / 12; ntl = wg - mt * 12;
        m0 = mt * 256; n0 = ntl * 256;
        A = Ag; Bm = Bg; LDA = DM; LDB = DM; start = 0; cnt = 16;
    } else if (EPI == 1) {
        // lower-tri 256x256 tiles: f = ti(ti+1)/2 + tj, f in 0..35
        z = blockIdx.z;
        const int f = blockIdx.x;
        int ti = (int)((sqrtf(8.f * f + 1.f) - 1.f) * 0.5f);
        while ((ti + 1) * (ti + 2) / 2 <= f) ti++;
        while (ti * (ti + 1) / 2 > f) ti--;
        const int tj = f - ti * (ti + 1) / 2;
        m0 = ti * 256; n0 = tj * 256;
        A = Ag + (size_t)z * SEQ * DM; Bm = Bg + (size_t)z * SEQ * DM;
        LDA = DM; LDB = DM; start = 0; cnt = 16;
    } else {
        // K-split work items: w<4 -> ti=w whole; else ti=4+((w-4)>>1), seg=(w-4)&1
        z = blockIdx.z;
        const int wrk = blockIdx.x;
        int ti, seg;
        if (wrk < 4) { ti = wrk; seg = -1; start = 0; cnt = 4 * (ti + 1); atom = 0; }
        else { const int e = wrk - 4; ti = 4 + (e >> 1); seg = e & 1;
               const int NT = 4 * (ti + 1); cnt = NT >> 1; start = seg * cnt; atom = 1; }
        m0 = ti * 256; n0 = blockIdx.y * 256;
        A = Ag + (size_t)z * SEQ * SEQ; Bm = Bg + (size_t)z * DM * SEQ;
        LDA = SEQ; LDB = SEQ;
    }

    const int t    = threadIdx.x;
    const int w    = t >> 6;          // wave 0..7
    const int lane = t & 63;
    const int wr   = w >> 2, wc = w & 3;   // 2M x 4N
    const int r    = lane & 15, q = lane >> 4;

    const int srow = lane >> 3;                       // staging row 0..7
    const int scol = ((lane & 7) ^ srow) << 3;        // inverse-swizzled global col

    const int sk0 = ((0 + q) ^ (r & 7)) * 8;          // kk=0 read slot
    const int sk1 = ((4 + q) ^ (r & 7)) * 8;          // kk=1 read slot
    const int aRd = wr * 8192 + r * 64;               // + (ib+ii)*16*64 + skX
    const int bRd = 16384 + (wc >> 1) * 8192 + ((wc & 1) * 64 + r) * 64;

    floatx4 acc[8][4];
#pragma unroll
    for (int i = 0; i < 8; i++)
#pragma unroll
        for (int j = 0; j < 4; j++)
            acc[i][j] = (floatx4){0.f, 0.f, 0.f, 0.f};

    // stage one [128][64] chunk (2 gloads/thread), proven layout
#define STGC(G, R0, LD, KB, CB) do { \
    gload16((G) + (size_t)((R0) + w * 16 + srow)     * (LD) + (KB) + scol, &lds[(CB) + w * 1024]); \
    gload16((G) + (size_t)((R0) + w * 16 + srow + 8) * (LD) + (KB) + scol, &lds[(CB) + w * 1024 + 512]); \
  } while (0)

#define RD_A(IB, SK) do { \
    af0 = *(const short8*)&lds[cb + aRd + ((IB) + 0) * 1024 + (SK)]; \
    af1 = *(const short8*)&lds[cb + aRd + ((IB) + 1) * 1024 + (SK)]; \
    af2 = *(const short8*)&lds[cb + aRd + ((IB) + 2) * 1024 + (SK)]; \
    af3 = *(const short8*)&lds[cb + aRd + ((IB) + 3) * 1024 + (SK)]; \
  } while (0)
#define RD_B(SK) do { \
    bf0 = *(const short8*)&lds[cb + bRd + 0 * 1024 + (SK)]; \
    bf1 = *(const short8*)&lds[cb + bRd + 1 * 1024 + (SK)]; \
    bf2 = *(const short8*)&lds[cb + bRd + 2 * 1024 + (SK)]; \
    bf3 = *(const short8*)&lds[cb + bRd + 3 * 1024 + (SK)]; \
  } while (0)

#define ONE_MFMA(AC, AF, BF) do { \
    if (EPI == 0) (AC) = __builtin_amdgcn_mfma_f32_16x16x32_bf16((AF), (BF), (AC), 0, 0, 0); \
    else          (AC) = __builtin_amdgcn_mfma_f32_16x16x32_bf16((BF), (AF), (AC), 0, 0, 0); \
  } while (0)
#define MFMA16(IB) do { \
    ONE_MFMA(acc[(IB)+0][0], af0, bf0); ONE_MFMA(acc[(IB)+0][1], af0, bf1); \
    ONE_MFMA(acc[(IB)+0][2], af0, bf2); ONE_MFMA(acc[(IB)+0][3], af0, bf3); \
    ONE_MFMA(acc[(IB)+1][0], af1, bf0); ONE_MFMA(acc[(IB)+1][1], af1, bf1); \
    ONE_MFMA(acc[(IB)+1][2], af1, bf2); ONE_MFMA(acc[(IB)+1][3], af1, bf3); \
    ONE_MFMA(acc[(IB)+2][0], af2, bf0); ONE_MFMA(acc[(IB)+2][1], af2, bf1); \
    ONE_MFMA(acc[(IB)+2][2], af2, bf2); ONE_MFMA(acc[(IB)+2][3], af2, bf3); \
    ONE_MFMA(acc[(IB)+3][0], af3, bf0); ONE_MFMA(acc[(IB)+3][1], af3, bf1); \
    ONE_MFMA(acc[(IB)+3][2], af3, bf2); ONE_MFMA(acc[(IB)+3][3], af3, bf3); \
  } while (0)

#define PH_SYNC() do { \
    __builtin_amdgcn_s_barrier(); \
    asm volatile("s_waitcnt lgkmcnt(0)" ::: "memory"); \
    __builtin_amdgcn_sched_barrier(0); \
    __builtin_amdgcn_s_setprio(1); \
  } while (0)
#define PH_END() do { \
    __builtin_amdgcn_s_setprio(0); \
    __builtin_amdgcn_s_barrier(); \
  } while (0)

    // prologue: stage tile 'start' into buffer 0
    {
        const int kb = start * 64;
        STGC(A,  m0,       LDA, kb, 0);
        STGC(A,  m0 + 128, LDA, kb, 8192);
        STGC(Bm, n0,       LDB, kb, 16384);
        STGC(Bm, n0 + 128, LDB, kb, 24576);
        asm volatile("s_waitcnt vmcnt(0)" ::: "memory");
        __builtin_amdgcn_s_barrier();
    }

    short8 af0, af1, af2, af3, bf0, bf1, bf2, bf3;

    for (int tt = 0; tt < cnt; ++tt) {
        const int cb  = (tt & 1) * 32768;
        const int ob  = 32768 - cb;
        const int nkb = (tt + 1 < cnt ? start + tt + 1 : start) * 64;  // wrap: dead stage

        // phase 0: kk0, m-half 0 (+B kk0) | stage A chunks of t+1
        RD_A(0, sk0); RD_B(sk0);
        STGC(A, m0,       LDA, nkb, ob);
        STGC(A, m0 + 128, LDA, nkb, ob + 8192);
        PH_SYNC(); MFMA16(0); PH_END();

        // phase 1: kk0, m-half 1 | stage B chunks of t+1
        RD_A(4, sk0);
        STGC(Bm, n0,       LDB, nkb, ob + 16384);
        STGC(Bm, n0 + 128, LDB, nkb, ob + 24576);
        PH_SYNC(); MFMA16(4); PH_END();

        // phase 2: kk1, m-half 0 (+B kk1)
        RD_A(0, sk1); RD_B(sk1);
        PH_SYNC(); MFMA16(0); PH_END();

        // phase 3: kk1, m-half 1 | drain t+1's loads (issued >=2 phases ago)
        RD_A(4, sk1);
        asm volatile("s_waitcnt vmcnt(0)" ::: "memory");
        PH_SYNC(); MFMA16(4); PH_END();
    }
#undef STGC
#undef RD_A
#undef RD_B

    // ------------------------- epilogues -------------------------
    if (EPI == 0) {
        // unswapped: row = m0 + wr*128 + i*16 + q*4 + rr, col = n0 + wc*64 + j*16 + r
        const int gmb = m0 + wr * 128 + q * 4;
        const int gnb = n0 + wc * 64 + r;
        unsigned short* Qo  = (unsigned short*)P0;
        unsigned short* Ko  = (unsigned short*)P1;
        unsigned short* Vto = (unsigned short*)P2;
        if (ntl < 4) {
#pragma unroll
            for (int i = 0; i < 8; i++) {
                const int gm = gmb + i * 16;
#pragma unroll
                for (int j = 0; j < 4; j++) {
                    const int gn = gnb + j * 16;
#pragma unroll
                    for (int rr = 0; rr < 4; rr++)
                        Qo[(size_t)(gm + rr) * 1024 + gn] = f2b(acc[i][j][rr] * qscale);
                }
            }
        } else if (ntl < 8) {
#pragma unroll
            for (int i = 0; i < 8; i++) {
                const int gm = gmb + i * 16;
#pragma unroll
                for (int j = 0; j < 4; j++) {
                    const int gn = gnb + j * 16;
#pragma unroll
                    for (int rr = 0; rr < 4; rr++)
                        Ko[(size_t)(gm + rr) * 1024 + (gn - 1024)] = f2b(acc[i][j][rr]);
                }
            }
        } else {
#pragma unroll
            for (int i = 0; i < 8; i++) {
                const int gm = gmb + i * 16;
                const int b  = gm >> 11;
                const int s  = gm & 2047;          // 4 consecutive tokens via rr
#pragma unroll
                for (int j = 0; j < 4; j++) {
                    const int v = gnb + j * 16 - 2048;
                    *(ushort4*)&Vto[((size_t)(b * 1024 + v)) * 2048 + s] =
                        pack4(acc[i][j][0], acc[i][j][1], acc[i][j][2], acc[i][j][3]);
                }
            }
        }
    } else if (EPI == 1) {
        // swapped: row gm = m0 + wr*128 + i*16 + r, col gn = n0 + wc*64 + j*16 + q*4 + rr
        const int gmb = m0 + wr * 128 + r;
        const int gnb = n0 + wc * 64 + q * 4;
        unsigned short* E = (unsigned short*)P0 + (size_t)z * SEQ * SEQ;
        float* rs = rowsum + (size_t)z * SEQ;
#pragma unroll
        for (int i = 0; i < 8; i++) {
            const int gm = gmb + i * 16;
            float part = 0.f;
#pragma unroll
            for (int j = 0; j < 4; j++) {
                const int gn = gnb + j * 16;
                float e0 = (gn + 0 <= gm) ? __expf(acc[i][j][0]) : 0.f;
                float e1 = (gn + 1 <= gm) ? __expf(acc[i][j][1]) : 0.f;
                float e2 = (gn + 2 <= gm) ? __expf(acc[i][j][2]) : 0.f;
                float e3 = (gn + 3 <= gm) ? __expf(acc[i][j][3]) : 0.f;
                part += (e0 + e1) + (e2 + e3);
                *(ushort4*)&E[(size_t)gm * SEQ + gn] = pack4(e0, e1, e2, e3);
            }
            part += __shfl_xor(part, 16, 64);
            part += __shfl_xor(part, 32, 64);
            if (q == 0) atomicAdd(&rs[gm], part);
        }
    } else {
        const int gmb = m0 + wr * 128 + r;
        const int gnb = n0 + wc * 64 + q * 4;
        float* C = (float*)P0 + (size_t)z * SEQ * DM;
        const float* rs = rowsum + (size_t)z * SEQ;
#pragma unroll
        for (int i = 0; i < 8; i++) {
            const int gm = gmb + i * 16;
            const float inv = 1.0f / rs[gm];
            if (atom) {
#pragma unroll
                for (int j = 0; j < 4; j++) {
                    const int gn = gnb + j * 16;
#pragma unroll
                    for (int rr = 0; rr < 4; rr++)
                        atomicAdd(&C[(size_t)gm * DM + gn + rr], acc[i][j][rr] * inv);
                }
            } else {
#pragma unroll
                for (int j = 0; j < 4; j++) {
                    const int gn = gnb + j * 16;
                    float4 o;
                    o.x = acc[i][j][0] * inv;
                    o.y = acc[i][j][1] * inv;
                    o.z = acc[i][j][2] * inv;
                    o.w = acc[i][j][3] * inv;
                    *(float4*)&C[(size_t)gm * DM + gn] = o;
                }
            }
        }
    }
}

extern "C" void kernel_launch(void* const* d_in, const int* in_sizes, int n_in,
                              void* d_out, int out_size, void* d_ws, size_t ws_size,
                              hipStream_t stream) {
    (void)in_sizes; (void)n_in; (void)out_size; (void)ws_size;
    const float* x  = (const float*)d_in[0];
    // d_in[1] = mask (causal; implicit — unused)
    const float* Wq = (const float*)d_in[2];
    const float* Wk = (const float*)d_in[3];
    const float* Wv = (const float*)d_in[4];

    char* base = (char*)d_ws;
    size_t off = 0;
    auto alloc = [&](size_t n) { char* p = base + off; off += (n + 255) & ~(size_t)255; return p; };

    unsigned short* xb   = (unsigned short*)alloc((size_t)NBAT * SEQ * DM * 2);  // 16.8 MB
    unsigned short* wall = (unsigned short*)alloc((size_t)3 * DM * DM * 2);      // 6.3 MB
    unsigned short* Qb   = (unsigned short*)alloc((size_t)NBAT * SEQ * DM * 2);  // scaled 1/32
    unsigned short* Kb   = (unsigned short*)alloc((size_t)NBAT * SEQ * DM * 2);
    unsigned short* Vtb  = (unsigned short*)alloc((size_t)NBAT * DM * SEQ * 2);  // [b][v][s]
    unsigned short* E    = (unsigned short*)alloc((size_t)NBAT * SEQ * SEQ * 2); // 33.5 MB
    float*          rsum = (float*)alloc((size_t)NBAT * SEQ * 4);

    // 1) fused prep: casts + rowsum zero + d_out upper-half zero (15392 blocks)
    prep<<<dim3(15392), dim3(256), 0, stream>>>(
        (const float4*)x, (const float4*)Wq, (const float4*)Wk, (const float4*)Wv,
        (ushort4*)xb, (ushort4*)wall, rsum, (float4*)d_out);

    // 2) fused QKV projection: 256^2 8-phase; 32x12 = 384 blocks
    gemm8p<0><<<dim3(384), dim3(512), 0, stream>>>(
        xb, wall, Qb, Kb, Vtb, nullptr, 0.03125f);

    // 3) E = exp(Q K^T) causal + rowsum: 36 tri-tiles x 4 batches = 144 blocks (1 round)
    gemm8p<1><<<dim3(36, 1, NBAT), dim3(512), 0, stream>>>(
        Qb, Kb, E, nullptr, nullptr, rsum, 0.f);

    // 4) out = (E Vt^T)/rowsum, K-split balanced: 12 work x 4 n x 4 z = 192 blocks (1 round)
    gemm8p<2><<<dim3(12, 4, NBAT), dim3(512), 0, stream>>>(
        E, Vtb, d_out, nullptr, nullptr, rsum, 0.f);
}

// Round 8
// 257.231 us; speedup vs baseline: 1.3844x; 1.3844x over previous
//
#include <hip/hip_runtime.h>
#include <hip/hip_bf16.h>
#include <stdint.h>

// Shapes (fixed): B=4, S=2048, D_MODEL=D_K=D_V=1024
#define SEQ   2048
#define DM    1024
#define NBAT  4

typedef __attribute__((ext_vector_type(8))) short  short8;   // 8 bf16 = 4 VGPRs (MFMA A/B frag)
typedef __attribute__((ext_vector_type(4))) float  floatx4;  // MFMA C/D frag

__device__ __forceinline__ unsigned short f2b(float f) {
    __hip_bfloat16 h = __float2bfloat16(f);
    unsigned short r;
    __builtin_memcpy(&r, &h, 2);
    return r;
}

__device__ __forceinline__ ushort4 pack4(float a, float b, float c, float d) {
    ushort4 u; u.x = f2b(a); u.y = f2b(b); u.z = f2b(c); u.w = f2b(d); return u;
}

// async global->LDS, 16B per lane. dst must be wave-uniform base (lane*16 added by HW).
__device__ __forceinline__ void gload16(const void* g, void* s) {
    __builtin_amdgcn_global_load_lds(
        (const __attribute__((address_space(1))) unsigned int*)(uintptr_t)g,
        (__attribute__((address_space(3))) unsigned int*)(uintptr_t)s,
        16, 0, 0);
}

// One fused prep dispatch: x cast (blocks 0..8191), Wq/Wk/Wv cast into contiguous
// wall[3*DM,DM] (blocks 8192..11263), rowsum zero (blocks 11264..11295).
__global__ void prep(const float4* __restrict__ x,
                     const float4* __restrict__ w0, const float4* __restrict__ w1,
                     const float4* __restrict__ w2,
                     ushort4* __restrict__ xb, ushort4* __restrict__ wall,
                     float* __restrict__ rsum)
{
    const int b = blockIdx.x;
    const int t = threadIdx.x;
    if (b < 8192) {
        const int i = b * 256 + t;
        float4 f = x[i];
        xb[i] = pack4(f.x, f.y, f.z, f.w);
    } else if (b < 11264) {
        const int idx  = b - 8192;
        const int wsel = idx >> 10;
        const int i    = (idx & 1023) * 256 + t;
        const float4* src = (wsel == 0) ? w0 : (wsel == 1) ? w1 : w2;
        float4 f = src[i];
        wall[(size_t)wsel * 262144 + i] = pack4(f.x, f.y, f.z, f.w);
    } else {
        rsum[(b - 11264) * 256 + t] = 0.f;
    }
}

// ---------------------------------------------------------------------------
// 256x256 GEMM core, R7/R8: R6's verified geometry under R5's measured
// schedule. BM=BN=256, BK=64, 8 waves (2M x 4N, wave tile 128x64 -> 64 MFMA /
// 24 ds_read per wave per K-tile). LDS = 2 x 64 KB double buffer; chunk =
// [128][64] bf16 R0-proven zero-conflict layout (piece slot s of row R holds
// piece s^(R&7), reads use slot (kk*4+q)^(r&7)).
// Per K-tile: { vmcnt(0) [waits loads staged ONE FULL TILE ago ~1600+cy > HBM
// latency -> cheap, unlike R6's 500-cy drain]; barrier; 12 ds_read kk0;
// STG 4 chunks of t+1 -> other buf; setprio(1); 32 MFMA kk0; 12 ds_read kk1;
// 32 MFMA kk1; setprio(0) }. Hazards: RAW via top vmcnt+barrier; WAR: any
// wave's STG(t+2)->buf[p] follows barrier(t+1), which follows all waves'
// reads(t) completion (lgkm drained before their last MFMA of tile t).
// EPI 0: QKV epilogue (unswapped). EPI 1: scores (swapped, exp causal + rowsum).
// ---------------------------------------------------------------------------
template<int EPI>
__global__ __launch_bounds__(512, 2) void gemm256(
    const unsigned short* __restrict__ Ag, const unsigned short* __restrict__ Bg,
    void* __restrict__ P0, void* __restrict__ P1, void* __restrict__ P2,
    float* __restrict__ rowsum, float qscale)
{
    __shared__ __align__(16) unsigned short lds[65536];   // 128 KB

    int m0, n0, ntl = 0, z = 0;
    const unsigned short* A;
    const unsigned short* Bm;

    if (EPI == 0) {
        // 384 blocks = 8 XCDs x 48, bijective, mt-major per XCD.
        const int bid = blockIdx.x;
        const int wg  = (bid & 7) * 48 + (bid >> 3);
        const int mt  = wg / 12; ntl = wg - mt * 12;
        m0 = mt * 256; n0 = ntl * 256;
        A = Ag; Bm = Bg;
    } else {
        // lower-tri 256x256 tiles: f = ti(ti+1)/2 + tj, f in 0..35
        z = blockIdx.z;
        const int f = blockIdx.x;
        int ti = (int)((sqrtf(8.f * f + 1.f) - 1.f) * 0.5f);
        while ((ti + 1) * (ti + 2) / 2 <= f) ti++;
        while (ti * (ti + 1) / 2 > f) ti--;
        const int tj = f - ti * (ti + 1) / 2;
        m0 = ti * 256; n0 = tj * 256;
        A = Ag + (size_t)z * SEQ * DM; Bm = Bg + (size_t)z * SEQ * DM;
    }

    const int t    = threadIdx.x;
    const int w    = t >> 6;          // wave 0..7
    const int lane = t & 63;
    const int wr   = w >> 2, wc = w & 3;   // 2M x 4N
    const int r    = lane & 15, q = lane >> 4;

    const int srow = lane >> 3;                       // staging row 0..7
    const int scol = ((lane & 7) ^ srow) << 3;        // inverse-swizzled global col

    const int sk0 = ((0 + q) ^ (r & 7)) * 8;          // kk=0 read slot
    const int sk1 = ((4 + q) ^ (r & 7)) * 8;          // kk=1 read slot
    const int aRd = wr * 8192 + r * 64;               // A chunk (wr) + row base
    const int bRd = 16384 + (wc >> 1) * 8192 + ((wc & 1) * 64 + r) * 64;

    floatx4 acc[8][4];
#pragma unroll
    for (int i = 0; i < 8; i++)
#pragma unroll
        for (int j = 0; j < 4; j++)
            acc[i][j] = (floatx4){0.f, 0.f, 0.f, 0.f};

    // stage one [128][64] chunk (2 gloads/thread), R0-proven layout
#define STGC(G, R0, KB, CB) do { \
    gload16((G) + (size_t)((R0) + w * 16 + srow)     * DM + (KB) + scol, &lds[(CB) + w * 1024]); \
    gload16((G) + (size_t)((R0) + w * 16 + srow + 8) * DM + (KB) + scol, &lds[(CB) + w * 1024 + 512]); \
  } while (0)
#define STG4(KB, OB) do { \
    STGC(A,  m0,       (KB), (OB)); \
    STGC(A,  m0 + 128, (KB), (OB) + 8192); \
    STGC(Bm, n0,       (KB), (OB) + 16384); \
    STGC(Bm, n0 + 128, (KB), (OB) + 24576); \
  } while (0)

#define ONE_MFMA(AC, AF, BF) do { \
    if (EPI == 0) (AC) = __builtin_amdgcn_mfma_f32_16x16x32_bf16((AF), (BF), (AC), 0, 0, 0); \
    else          (AC) = __builtin_amdgcn_mfma_f32_16x16x32_bf16((BF), (AF), (AC), 0, 0, 0); \
  } while (0)

    // prologue: stage tile 0 into buffer 0 (the loop-top vmcnt(0) waits it once)
    STG4(0, 0);

    for (int tt = 0; tt < 16; ++tt) {
        const int cb  = (tt & 1) * 32768;
        const int ob  = 32768 - cb;
        const int nkb = (tt + 1 < 16 ? tt + 1 : 0) * 64;   // wrap: dead stage

        asm volatile("s_waitcnt vmcnt(0)" ::: "memory");
        __builtin_amdgcn_s_barrier();

        short8 a0[8], b0[4];
#pragma unroll
        for (int i = 0; i < 8; i++)
            a0[i] = *(const short8*)&lds[cb + aRd + i * 1024 + sk0];
#pragma unroll
        for (int j = 0; j < 4; j++)
            b0[j] = *(const short8*)&lds[cb + bRd + j * 1024 + sk0];

        STG4(nkb, ob);

        __builtin_amdgcn_s_setprio(1);
#pragma unroll
        for (int i = 0; i < 8; i++)
#pragma unroll
            for (int j = 0; j < 4; j++)
                ONE_MFMA(acc[i][j], a0[i], b0[j]);

        short8 a1[8], b1[4];
#pragma unroll
        for (int i = 0; i < 8; i++)
            a1[i] = *(const short8*)&lds[cb + aRd + i * 1024 + sk1];
#pragma unroll
        for (int j = 0; j < 4; j++)
            b1[j] = *(const short8*)&lds[cb + bRd + j * 1024 + sk1];
#pragma unroll
        for (int i = 0; i < 8; i++)
#pragma unroll
            for (int j = 0; j < 4; j++)
                ONE_MFMA(acc[i][j], a1[i], b1[j]);
        __builtin_amdgcn_s_setprio(0);
    }
#undef STGC
#undef STG4
#undef ONE_MFMA

    // ------------------------- epilogues (R6-verified index math) ----------
    if (EPI == 0) {
        // unswapped: row = m0 + wr*128 + i*16 + q*4 + rr, col = n0 + wc*64 + j*16 + r
        const int gmb = m0 + wr * 128 + q * 4;
        const int gnb = n0 + wc * 64 + r;
        unsigned short* Qo  = (unsigned short*)P0;
        unsigned short* Ko  = (unsigned short*)P1;
        unsigned short* Vto = (unsigned short*)P2;
        if (ntl < 4) {
#pragma unroll
            for (int i = 0; i < 8; i++) {
                const int gm = gmb + i * 16;
#pragma unroll
                for (int j = 0; j < 4; j++) {
                    const int gn = gnb + j * 16;
#pragma unroll
                    for (int rr = 0; rr < 4; rr++)
                        Qo[(size_t)(gm + rr) * 1024 + gn] = f2b(acc[i][j][rr] * qscale);
                }
            }
        } else if (ntl < 8) {
#pragma unroll
            for (int i = 0; i < 8; i++) {
                const int gm = gmb + i * 16;
#pragma unroll
                for (int j = 0; j < 4; j++) {
                    const int gn = gnb + j * 16;
#pragma unroll
                    for (int rr = 0; rr < 4; rr++)
                        Ko[(size_t)(gm + rr) * 1024 + (gn - 1024)] = f2b(acc[i][j][rr]);
                }
            }
        } else {
#pragma unroll
            for (int i = 0; i < 8; i++) {
                const int gm = gmb + i * 16;
                const int b  = gm >> 11;
                const int s  = gm & 2047;          // 4 consecutive tokens via rr
#pragma unroll
                for (int j = 0; j < 4; j++) {
                    const int v = gnb + j * 16 - 2048;
                    *(ushort4*)&Vto[((size_t)(b * 1024 + v)) * 2048 + s] =
                        pack4(acc[i][j][0], acc[i][j][1], acc[i][j][2], acc[i][j][3]);
                }
            }
        }
    } else {
        // swapped: row gm = m0 + wr*128 + i*16 + r, col gn = n0 + wc*64 + j*16 + q*4 + rr
        const int gmb = m0 + wr * 128 + r;
        const int gnb = n0 + wc * 64 + q * 4;
        unsigned short* E = (unsigned short*)P0 + (size_t)z * SEQ * SEQ;
        float* rs = rowsum + (size_t)z * SEQ;
#pragma unroll
        for (int i = 0; i < 8; i++) {
            const int gm = gmb + i * 16;
            float part = 0.f;
#pragma unroll
            for (int j = 0; j < 4; j++) {
                const int gn = gnb + j * 16;
                float e0 = (gn + 0 <= gm) ? __expf(acc[i][j][0]) : 0.f;
                float e1 = (gn + 1 <= gm) ? __expf(acc[i][j][1]) : 0.f;
                float e2 = (gn + 2 <= gm) ? __expf(acc[i][j][2]) : 0.f;
                float e3 = (gn + 3 <= gm) ? __expf(acc[i][j][3]) : 0.f;
                part += (e0 + e1) + (e2 + e3);
                *(ushort4*)&E[(size_t)gm * SEQ + gn] = pack4(e0, e1, e2, e3);
            }
            part += __shfl_xor(part, 16, 64);
            part += __shfl_xor(part, 32, 64);
            if (q == 0) atomicAdd(&rs[gm], part);
        }
    }
}

// ---------------------------------------------------------------------------
// PV GEMM (R5's measured kernel, verbatim): BM=256, BN=128, BK=64, 8 waves
// 4Mx2N, ring-3 (144 KB), vmcnt(6), R0 zero-conflict chunks, one barrier per
// K-tile, swapped operands. C = E*Vt^T / rowsum; kEnd = m0+256, heavy-first.
// ---------------------------------------------------------------------------
#define SLOTS 24576

__global__ __launch_bounds__(512, 2) void attn_pv(
    const unsigned short* __restrict__ Ag, const unsigned short* __restrict__ Bg,
    float* __restrict__ Cv, const float* __restrict__ rowsum)
{
    __shared__ __align__(16) unsigned short lds[3 * SLOTS];   // 144 KB

    const int z = blockIdx.z;
    const int m0 = (int)(gridDim.y - 1 - blockIdx.y) * 256;   // heavy first
    const int n0 = blockIdx.x * 128;

    const unsigned short* A  = Ag + (size_t)z * SEQ * SEQ;
    const unsigned short* Bm = Bg + (size_t)z * DM * SEQ;
    const int NT = (m0 + 256) / 64;

    const int t    = threadIdx.x;
    const int w    = t >> 6;
    const int lane = t & 63;
    const int wr   = w >> 1, wc = w & 1;
    const int r    = lane & 15, q = lane >> 4;

    const int srow = lane >> 3;
    const int scol = ((lane & 7) ^ srow) << 3;

    const int aoff = (wr >> 1) * 8192 + ((wr & 1) * 64 + r) * 64;
    const int boff = 16384 + (wc * 64 + r) * 64;
    const int sk0  = ((0 + q) ^ (r & 7)) * 8;
    const int sk1  = ((4 + q) ^ (r & 7)) * 8;

    floatx4 acc[4][4];
#pragma unroll
    for (int i = 0; i < 4; i++)
#pragma unroll
        for (int j = 0; j < 4; j++)
            acc[i][j] = (floatx4){0.f, 0.f, 0.f, 0.f};

#define ASTG(KB, SL) do { \
    gload16(A + (size_t)(m0 +       w * 16 + srow) * SEQ + (KB) + scol, &lds[(SL) +         w * 1024]); \
    gload16(A + (size_t)(m0 +   8 + w * 16 + srow) * SEQ + (KB) + scol, &lds[(SL) +         w * 1024 + 512]); \
    gload16(A + (size_t)(m0 + 128 + w * 16 + srow) * SEQ + (KB) + scol, &lds[(SL) + 8192 +  w * 1024]); \
    gload16(A + (size_t)(m0 + 136 + w * 16 + srow) * SEQ + (KB) + scol, &lds[(SL) + 8192 +  w * 1024 + 512]); \
  } while (0)
#define BSTG(KB, SL) do { \
    gload16(Bm + (size_t)(n0 +      w * 16 + srow) * SEQ + (KB) + scol, &lds[(SL) + 16384 + w * 1024]); \
    gload16(Bm + (size_t)(n0 +  8 + w * 16 + srow) * SEQ + (KB) + scol, &lds[(SL) + 16384 + w * 1024 + 512]); \
  } while (0)

    ASTG(0, 0);
    BSTG(0, 0);
    ASTG(64, SLOTS);
    BSTG(64, SLOTS);
    asm volatile("s_waitcnt vmcnt(6)" ::: "memory");
    __builtin_amdgcn_s_barrier();

    for (int tt = 0; tt < NT; ++tt) {
        const int sl  = (tt % 3) * SLOTS;
        const int nsl = ((tt + 2) % 3) * SLOTS;
        const int nkb = (tt + 2 < NT) ? (tt + 2) * 64 : 0;

        const int aB = sl + aoff;
        const int bB = sl + boff;
        short8 a00 = *(const short8*)&lds[aB + sk0 +    0];
        short8 a10 = *(const short8*)&lds[aB + sk0 + 1024];
        short8 a20 = *(const short8*)&lds[aB + sk0 + 2048];
        short8 a30 = *(const short8*)&lds[aB + sk0 + 3072];
        short8 b00 = *(const short8*)&lds[bB + sk0 +    0];
        short8 b10 = *(const short8*)&lds[bB + sk0 + 1024];
        short8 b20 = *(const short8*)&lds[bB + sk0 + 2048];
        short8 b30 = *(const short8*)&lds[bB + sk0 + 3072];
        short8 a01 = *(const short8*)&lds[aB + sk1 +    0];
        short8 a11 = *(const short8*)&lds[aB + sk1 + 1024];
        short8 a21 = *(const short8*)&lds[aB + sk1 + 2048];
        short8 a31 = *(const short8*)&lds[aB + sk1 + 3072];
        short8 b01 = *(const short8*)&lds[bB + sk1 +    0];
        short8 b11 = *(const short8*)&lds[bB + sk1 + 1024];
        short8 b21 = *(const short8*)&lds[bB + sk1 + 2048];
        short8 b31 = *(const short8*)&lds[bB + sk1 + 3072];

        ASTG(nkb, nsl);
        BSTG(nkb, nsl);
        asm volatile("s_waitcnt vmcnt(6)" ::: "memory");
        __builtin_amdgcn_s_barrier();

        __builtin_amdgcn_s_setprio(1);
        acc[0][0] = __builtin_amdgcn_mfma_f32_16x16x32_bf16(b00, a00, acc[0][0], 0, 0, 0);
        acc[0][1] = __builtin_amdgcn_mfma_f32_16x16x32_bf16(b10, a00, acc[0][1], 0, 0, 0);
        acc[0][2] = __builtin_amdgcn_mfma_f32_16x16x32_bf16(b20, a00, acc[0][2], 0, 0, 0);
        acc[0][3] = __builtin_amdgcn_mfma_f32_16x16x32_bf16(b30, a00, acc[0][3], 0, 0, 0);
        acc[1][0] = __builtin_amdgcn_mfma_f32_16x16x32_bf16(b00, a10, acc[1][0], 0, 0, 0);
        acc[1][1] = __builtin_amdgcn_mfma_f32_16x16x32_bf16(b10, a10, acc[1][1], 0, 0, 0);
        acc[1][2] = __builtin_amdgcn_mfma_f32_16x16x32_bf16(b20, a10, acc[1][2], 0, 0, 0);
        acc[1][3] = __builtin_amdgcn_mfma_f32_16x16x32_bf16(b30, a10, acc[1][3], 0, 0, 0);
        acc[2][0] = __builtin_amdgcn_mfma_f32_16x16x32_bf16(b00, a20, acc[2][0], 0, 0, 0);
        acc[2][1] = __builtin_amdgcn_mfma_f32_16x16x32_bf16(b10, a20, acc[2][1], 0, 0, 0);
        acc[2][2] = __builtin_amdgcn_mfma_f32_16x16x32_bf16(b20, a20, acc[2][2], 0, 0, 0);
        acc[2][3] = __builtin_amdgcn_mfma_f32_16x16x32_bf16(b30, a20, acc[2][3], 0, 0, 0);
        acc[3][0] = __builtin_amdgcn_mfma_f32_16x16x32_bf16(b00, a30, acc[3][0], 0, 0, 0);
        acc[3][1] = __builtin_amdgcn_mfma_f32_16x16x32_bf16(b10, a30, acc[3][1], 0, 0, 0);
        acc[3][2] = __builtin_amdgcn_mfma_f32_16x16x32_bf16(b20, a30, acc[3][2], 0, 0, 0);
        acc[3][3] = __builtin_amdgcn_mfma_f32_16x16x32_bf16(b30, a30, acc[3][3], 0, 0, 0);
        acc[0][0] = __builtin_amdgcn_mfma_f32_16x16x32_bf16(b01, a01, acc[0][0], 0, 0, 0);
        acc[0][1] = __builtin_amdgcn_mfma_f32_16x16x32_bf16(b11, a01, acc[0][1], 0, 0, 0);
        acc[0][2] = __builtin_amdgcn_mfma_f32_16x16x32_bf16(b21, a01, acc[0][2], 0, 0, 0);
        acc[0][3] = __builtin_amdgcn_mfma_f32_16x16x32_bf16(b31, a01, acc[0][3], 0, 0, 0);
        acc[1][0] = __builtin_amdgcn_mfma_f32_16x16x32_bf16(b01, a11, acc[1][0], 0, 0, 0);
        acc[1][1] = __builtin_amdgcn_mfma_f32_16x16x32_bf16(b11, a11, acc[1][1], 0, 0, 0);
        acc[1][2] = __builtin_amdgcn_mfma_f32_16x16x32_bf16(b21, a11, acc[1][2], 0, 0, 0);
        acc[1][3] = __builtin_amdgcn_mfma_f32_16x16x32_bf16(b31, a11, acc[1][3], 0, 0, 0);
        acc[2][0] = __builtin_amdgcn_mfma_f32_16x16x32_bf16(b01, a21, acc[2][0], 0, 0, 0);
        acc[2][1] = __builtin_amdgcn_mfma_f32_16x16x32_bf16(b11, a21, acc[2][1], 0, 0, 0);
        acc[2][2] = __builtin_amdgcn_mfma_f32_16x16x32_bf16(b21, a21, acc[2][2], 0, 0, 0);
        acc[2][3] = __builtin_amdgcn_mfma_f32_16x16x32_bf16(b31, a21, acc[2][3], 0, 0, 0);
        acc[3][0] = __builtin_amdgcn_mfma_f32_16x16x32_bf16(b01, a31, acc[3][0], 0, 0, 0);
        acc[3][1] = __builtin_amdgcn_mfma_f32_16x16x32_bf16(b11, a31, acc[3][1], 0, 0, 0);
        acc[3][2] = __builtin_amdgcn_mfma_f32_16x16x32_bf16(b21, a31, acc[3][2], 0, 0, 0);
        acc[3][3] = __builtin_amdgcn_mfma_f32_16x16x32_bf16(b31, a31, acc[3][3], 0, 0, 0);
        __builtin_amdgcn_s_setprio(0);
    }
#undef ASTG
#undef BSTG

    // swapped epilogue: row gm = m0 + wr*64 + i*16 + r, col gn = n0 + wc*64 + j*16 + q*4 + rr
    const int gmb = m0 + wr * 64 + r;
    const int gnb = n0 + wc * 64 + q * 4;
    float* C = Cv + (size_t)z * SEQ * DM;
    const float* rs = rowsum + (size_t)z * SEQ;
#pragma unroll
    for (int i = 0; i < 4; i++) {
        const int gm = gmb + i * 16;
        const float inv = 1.0f / rs[gm];
#pragma unroll
        for (int j = 0; j < 4; j++) {
            const int gn = gnb + j * 16;
            float4 o;
            o.x = acc[i][j][0] * inv;
            o.y = acc[i][j][1] * inv;
            o.z = acc[i][j][2] * inv;
            o.w = acc[i][j][3] * inv;
            *(float4*)&C[(size_t)gm * DM + gn] = o;
        }
    }
}

extern "C" void kernel_launch(void* const* d_in, const int* in_sizes, int n_in,
                              void* d_out, int out_size, void* d_ws, size_t ws_size,
                              hipStream_t stream) {
    (void)in_sizes; (void)n_in; (void)out_size; (void)ws_size;
    const float* x  = (const float*)d_in[0];
    // d_in[1] = mask (causal; implicit — unused)
    const float* Wq = (const float*)d_in[2];
    const float* Wk = (const float*)d_in[3];
    const float* Wv = (const float*)d_in[4];

    char* base = (char*)d_ws;
    size_t off = 0;
    auto alloc = [&](size_t n) { char* p = base + off; off += (n + 255) & ~(size_t)255; return p; };

    unsigned short* xb   = (unsigned short*)alloc((size_t)NBAT * SEQ * DM * 2);  // 16.8 MB
    unsigned short* wall = (unsigned short*)alloc((size_t)3 * DM * DM * 2);      // 6.3 MB
    unsigned short* Qb   = (unsigned short*)alloc((size_t)NBAT * SEQ * DM * 2);  // scaled 1/32
    unsigned short* Kb   = (unsigned short*)alloc((size_t)NBAT * SEQ * DM * 2);
    unsigned short* Vtb  = (unsigned short*)alloc((size_t)NBAT * DM * SEQ * 2);  // [b][v][s]
    unsigned short* E    = (unsigned short*)alloc((size_t)NBAT * SEQ * SEQ * 2); // 33.5 MB
    float*          rsum = (float*)alloc((size_t)NBAT * SEQ * 4);

    // 1) fused prep: casts + rowsum zero (11296 blocks)
    prep<<<dim3(11296), dim3(256), 0, stream>>>(
        (const float4*)x, (const float4*)Wq, (const float4*)Wk, (const float4*)Wv,
        (ushort4*)xb, (ushort4*)wall, rsum);

    // 2) fused QKV projection: 256^2 dbuf core; 32x12 = 384 blocks
    gemm256<0><<<dim3(384), dim3(512), 0, stream>>>(
        xb, wall, Qb, Kb, Vtb, nullptr, 0.03125f);

    // 3) E = exp(Q K^T) causal + rowsum: 36 tri-tiles x 4 batches = 144 blocks (1 round)
    gemm256<1><<<dim3(36, 1, NBAT), dim3(512), 0, stream>>>(
        Qb, Kb, E, nullptr, nullptr, rsum, 0.f);

    // 4) out = (E Vt^T)/rowsum: 8x8x4 = 256 blocks (1 round), heavy-first (R5 kernel)
    attn_pv<<<dim3(DM / 128, SEQ / 256, NBAT), dim3(512), 0, stream>>>(
        E, Vtb, (float*)d_out, rsum);
}